// Round 9
// baseline (1293.764 us; speedup 1.0000x reference)
//
#include <hip/hip_runtime.h>
#include <hip/hip_bf16.h>

#define T_ 2048
#define D_ 2560
#define H_ 8
#define KV_ 4
#define HD_ 256
#define S_ 8192
#define PREV_ 4096
#define SEFF_ 6144
#define SCALE_ 0.0625f
#define LOG2E_ 1.44269504088896f
#define NS_ 4            // attention key-dim splits

typedef __attribute__((ext_vector_type(8))) short short8;
typedef __attribute__((ext_vector_type(4))) float floatx4;

// load 8 contiguous elements as bf16 short8 (converting if fp32 source)
__device__ inline short8 ld8(const __hip_bfloat16* p) { return *(const short8*)p; }
__device__ inline short8 ld8(const float* p) {
    float4 a = *(const float4*)p;
    float4 b = *(const float4*)(p + 4);
    union { short8 s; __hip_bfloat16 h[8]; } u;
    u.h[0] = __hip_bfloat16(a.x); u.h[1] = __hip_bfloat16(a.y);
    u.h[2] = __hip_bfloat16(a.z); u.h[3] = __hip_bfloat16(a.w);
    u.h[4] = __hip_bfloat16(b.x); u.h[5] = __hip_bfloat16(b.y);
    u.h[6] = __hip_bfloat16(b.z); u.h[7] = __hip_bfloat16(b.w);
    return u.s;
}

__device__ inline short bfbits(float x) {
    __hip_bfloat16 h(x);
    short s;
    __builtin_memcpy(&s, &h, 2);
    return s;
}

__device__ inline float b2f(short u) {
    unsigned int x = ((unsigned int)(unsigned short)u) << 16;
    float f; __builtin_memcpy(&f, &x, 4); return f;
}

// ---------------- GEMM: C[M,N] = A[M,K] * B[N,K]^T  (inputs cast to bf16, fp32 acc)
template<typename TA, typename TB, bool BF16_OUT>
__global__ __launch_bounds__(256) void gemm_bt(const TA* __restrict__ A,
                                               const TB* __restrict__ Bm,
                                               void* __restrict__ Cout,
                                               int M, int N, int K) {
    __shared__ __align__(16) __hip_bfloat16 As[128 * 40];
    __shared__ __align__(16) __hip_bfloat16 Bs[128 * 40];
    const int tid = threadIdx.x;
    const int bm = (int)blockIdx.y * 128, bn = (int)blockIdx.x * 128;
    const int w = tid >> 6, lane = tid & 63, quad = lane >> 4, lr = lane & 15;
    const int wm = (w >> 1) * 64, wn = (w & 1) * 64;
    floatx4 acc[4][4] = {};
    const int row = tid >> 2;          // 0..63
    const int col = (tid & 3) * 8;     // 0,8,16,24

    for (int k0 = 0; k0 < K; k0 += 32) {
        __syncthreads();
        for (int p = 0; p < 2; ++p) {
            int r = row + p * 64;
            *(short8*)(&As[r * 40 + col]) = ld8(&A[(size_t)(bm + r) * K + k0 + col]);
            *(short8*)(&Bs[r * 40 + col]) = ld8(&Bm[(size_t)(bn + r) * K + k0 + col]);
        }
        __syncthreads();
        short8 a[4], b[4];
        for (int mi = 0; mi < 4; ++mi)
            a[mi] = *(const short8*)(&As[(wm + mi * 16 + lr) * 40 + quad * 8]);
        for (int ni = 0; ni < 4; ++ni)
            b[ni] = *(const short8*)(&Bs[(wn + ni * 16 + lr) * 40 + quad * 8]);
        for (int mi = 0; mi < 4; ++mi)
            for (int ni = 0; ni < 4; ++ni)
                acc[mi][ni] = __builtin_amdgcn_mfma_f32_16x16x32_bf16(a[mi], b[ni], acc[mi][ni], 0, 0, 0);
    }
    // C/D layout: col = lane&15, row = quad*4 + reg
    for (int mi = 0; mi < 4; ++mi)
        for (int ni = 0; ni < 4; ++ni)
            for (int r = 0; r < 4; ++r) {
                int m = bm + wm + mi * 16 + quad * 4 + r;
                int n = bn + wn + ni * 16 + lr;
                float v = acc[mi][ni][r];
                if (BF16_OUT) ((__hip_bfloat16*)Cout)[(size_t)m * N + n] = __hip_bfloat16(v);
                else          ((float*)Cout)[(size_t)m * N + n] = v;
            }
}

// ---------------- RMSNorm + RoPE (fp32), output bf16 into [head][t(+off)][256] layout
__global__ __launch_bounds__(256) void norm_rope(const float* __restrict__ src,  // [T][nh*256]
                                                 const float* __restrict__ scale,
                                                 const float* __restrict__ cosd,
                                                 const float* __restrict__ sind,
                                                 __hip_bfloat16* __restrict__ dst,
                                                 int nh, int smax, int toff) {
    const int rowid = blockIdx.x;
    const int t = rowid / nh, hh = rowid % nh;
    const int d = threadIdx.x;  // 0..255
    __shared__ float ybuf[256];
    __shared__ float wsum[4];
    float x = src[(size_t)t * (nh * 256) + hh * 256 + d];
    float ss = x * x;
    for (int m = 1; m < 64; m <<= 1) ss += __shfl_xor(ss, m);
    if ((d & 63) == 0) wsum[d >> 6] = ss;
    __syncthreads();
    float tot = wsum[0] + wsum[1] + wsum[2] + wsum[3];
    float inv = rsqrtf(tot * (1.0f / 256.0f) + 1e-6f);
    float y = x * inv * (1.0f + scale[d]);
    ybuf[d] = y;
    __syncthreads();
    float rot = (d < 128) ? -ybuf[d + 128] : ybuf[d - 128];
    float cv = cosd[(size_t)t * 256 + d];
    float sv = sind[(size_t)t * 256 + d];
    float out = y * cv + rot * sv;
    dst[((size_t)hh * smax + (t + toff)) * 256 + d] = __hip_bfloat16(out);
}

// ---------------- old K cache (fp32) -> Kc[g][s][256] bf16
__global__ __launch_bounds__(256) void merge_k(const float* __restrict__ kin,
                                               __hip_bfloat16* __restrict__ Kc) {
    int rid = blockIdx.x * 4 + (threadIdx.x >> 6);  // g*4096 + s
    int lane = threadIdx.x & 63;
    int g = rid >> 12, s = rid & 4095;
    float4 v = *(const float4*)&kin[((size_t)s * KV_ + g) * 256 + lane * 4];
    __hip_bfloat16* dst = &Kc[((size_t)g * SEFF_ + s) * 256 + lane * 4];
    union { unsigned long long u; __hip_bfloat16 h[4]; } pk;
    pk.h[0] = __hip_bfloat16(v.x); pk.h[1] = __hip_bfloat16(v.y);
    pk.h[2] = __hip_bfloat16(v.z); pk.h[3] = __hip_bfloat16(v.w);
    *(unsigned long long*)(void*)dst = pk.u;
}

// ---------------- V (old cache fp32 + new fp32 rows) -> Vt[g][d][s] bf16 (transposed)
__global__ __launch_bounds__(256) void transpose_v(const float* __restrict__ vin,
                                                   const float* __restrict__ vnew,
                                                   __hip_bfloat16* __restrict__ Vt) {
    __shared__ __hip_bfloat16 tile[64][65];
    const int g = blockIdx.z;
    const int d0 = blockIdx.y * 64;
    const int s0 = blockIdx.x * 64;
    const int tid = threadIdx.x;
    for (int p = 0; p < 16; ++p) {
        int idx = p * 256 + tid;
        int r = idx >> 6, cc = idx & 63;   // r = s offset, cc = d offset
        int s = s0 + r, d = d0 + cc;
        float v;
        if (s < PREV_) v = vin[((size_t)s * KV_ + g) * 256 + d];
        else           v = vnew[(size_t)(s - PREV_) * 1024 + g * 256 + d];
        tile[r][cc] = __hip_bfloat16(v);
    }
    __syncthreads();
    for (int p = 0; p < 16; ++p) {
        int idx = p * 256 + tid;
        int r = idx >> 6, cc = idx & 63;   // r = d offset, cc = s offset
        Vt[((size_t)g * 256 + d0 + r) * SEFF_ + s0 + cc] = tile[cc][r];
    }
}

// ---------------- flash attention v3: 2-head blocks, double-buffered LDS K,
// per-wave global V fragments (L2-served), split-s.
// Block = 1024 threads (16 waves): waves 0-7 -> head 2g rows, 8-15 -> head 2g+1.
__global__ __launch_bounds__(1024, 4) void attn(const __hip_bfloat16* __restrict__ Qr,  // [H][T][256]
                                                const __hip_bfloat16* __restrict__ Kc,  // [KV][SEFF][256]
                                                const __hip_bfloat16* __restrict__ Vt,  // [KV][256][SEFF]
                                                short* __restrict__ Po,                 // [H][128][NS][16][256]
                                                float* __restrict__ Pm,                 // [H][128][NS][16]
                                                float* __restrict__ Pl) {               // [H][128][NS][16]
    __shared__ __align__(16) short Ks[2][32 * 264];  // double-buffered K tile
    __shared__ __align__(16) short Pls[16][512];     // per-wave P transform buffer
    const int g = blockIdx.x;      // 0..3 (kv group)
    const int qb = blockIdx.y;     // 0..15 (128 rows each)
    const int ns = blockIdx.z;     // 0..NS_-1
    const int tid = threadIdx.x;   // 0..1023
    const int w = tid >> 6, lane = tid & 63, quad = lane >> 4, lr = lane & 15;
    const int hw = w >> 3, wl = w & 7;
    const int h = g * 2 + hw;
    const int qbase = qb * 128;
    const int t0 = qbase + wl * 16;

    const short* Qb = (const short*)Qr + ((size_t)h * T_ + t0) * 256;
    const short* Kg = (const short*)Kc + (size_t)g * SEFF_ * 256;
    const short* Vg = (const short*)Vt + (size_t)g * 256 * SEFF_;

    short8 aq[8];
    for (int kk = 0; kk < 8; ++kk)
        aq[kk] = *(const short8*)(&Qb[(size_t)lr * 256 + kk * 32 + quad * 8]);

    floatx4 o[16] = {};
    float mrow[4] = {-3e38f, -3e38f, -3e38f, -3e38f};
    float lrow[4] = {0.f, 0.f, 0.f, 0.f};
    const float c = SCALE_ * LOG2E_;

    const int nf_w = (PREV_ + t0) >> 5;                   // this wave's masked tile
    const int tiles_b = ((PREV_ + qbase + 112) >> 5) + 1; // block-uniform tile count
    const int per = (tiles_b + NS_ - 1) / NS_;
    const int tstart = ns * per;
    const int tend = min(tstart + per, tiles_b);
    short* pw = &Pls[w][0];

    // staging map: thread -> (key row, d chunk); 32 rows x 512B = 16KB, 16B/thread
    const int kr = tid >> 5, kc = (tid & 31) * 8;

    // prologue: stage tile tstart into buffer 0
    {
        short8 k0 = *(const short8*)&Kg[(size_t)(tstart * 32 + kr) * 256 + kc];
        *(short8*)&Ks[0][kr * 264 + kc] = k0;
    }
    __syncthreads();
    int cur = 0;

    for (int tile = tstart; tile < tend; ++tile) {
        const int s0 = tile * 32;
        const bool have_next = (tile + 1 < tend);
        short8 knext;
        if (have_next)
            knext = *(const short8*)&Kg[(size_t)((tile + 1) * 32 + kr) * 256 + kc];

        if (tile <= nf_w) {
            const bool masked = (tile == nf_w);
            floatx4 sc[2];
            for (int half = 0; half < 2; ++half) {
                const short* kp = &Ks[cur][(half * 16 + lr) * 264 + quad * 8];
                floatx4 accs = {0.f, 0.f, 0.f, 0.f};
                for (int kk = 0; kk < 8; ++kk) {
                    short8 bk = *(const short8*)(kp + kk * 32);
                    accs = __builtin_amdgcn_mfma_f32_16x16x32_bf16(aq[kk], bk, accs, 0, 0, 0);
                }
                sc[half] = accs;
            }
            float mnew[4];
            for (int r = 0; r < 4; ++r) {
                float v0 = sc[0][r] * c, v1 = sc[1][r] * c;
                if (masked) {
                    int limit = PREV_ + t0 + quad * 4 + r;
                    if (s0 + lr > limit)       v0 = -3e38f;
                    if (s0 + 16 + lr > limit)  v1 = -3e38f;
                }
                sc[0][r] = v0; sc[1][r] = v1;
                float mx = fmaxf(v0, v1);
                mx = fmaxf(mx, __shfl_xor(mx, 1));
                mx = fmaxf(mx, __shfl_xor(mx, 2));
                mx = fmaxf(mx, __shfl_xor(mx, 4));
                mx = fmaxf(mx, __shfl_xor(mx, 8));
                mnew[r] = fmaxf(mrow[r], mx);
            }
            float alpha[4];
            for (int r = 0; r < 4; ++r) { alpha[r] = exp2f(mrow[r] - mnew[r]); mrow[r] = mnew[r]; }
            for (int r = 0; r < 4; ++r) {
                float p0 = exp2f(sc[0][r] - mnew[r]);
                float p1 = exp2f(sc[1][r] - mnew[r]);
                sc[0][r] = p0; sc[1][r] = p1;
                float s = p0 + p1;
                s += __shfl_xor(s, 1);
                s += __shfl_xor(s, 2);
                s += __shfl_xor(s, 4);
                s += __shfl_xor(s, 8);
                lrow[r] = lrow[r] * alpha[r] + s;
            }
            bool need = (alpha[0] < 1.f) | (alpha[1] < 1.f) | (alpha[2] < 1.f) | (alpha[3] < 1.f);
            if (__any(need)) {
                for (int ni = 0; ni < 16; ++ni)
                    for (int r = 0; r < 4; ++r) o[ni][r] *= alpha[r];
            }
            // P: D-layout -> LDS -> A-layout (same-wave DS ops are HW-in-order;
            // the asm pins compiler ordering and waits out the writes).
            for (int half = 0; half < 2; ++half)
                for (int r = 0; r < 4; ++r)
                    pw[(quad * 4 + r) * 32 + half * 16 + lr] = bfbits(sc[half][r]);
            __asm__ volatile("s_waitcnt lgkmcnt(0)" ::: "memory");
            short8 ap = *(const short8*)(&pw[lr * 32 + quad * 8]);
            for (int ni = 0; ni < 16; ++ni) {
                short8 bv = *(const short8*)(&Vg[(size_t)(ni * 16 + lr) * SEFF_ + s0 + quad * 8]);
                o[ni] = __builtin_amdgcn_mfma_f32_16x16x32_bf16(ap, bv, o[ni], 0, 0, 0);
            }
        }

        if (have_next)
            *(short8*)&Ks[cur ^ 1][kr * 264 + kc] = knext;
        __syncthreads();
        cur ^= 1;
    }
    // partial epilogue: unnormalized o + (m, l)
    const int tq = qb * 8 + wl;  // 16-row tile index within head, 0..127
    const size_t pbase = (((size_t)h * 128 + tq) * NS_ + ns) * 16;
    for (int ni = 0; ni < 16; ++ni)
        for (int r = 0; r < 4; ++r)
            Po[(pbase + quad * 4 + r) * 256 + ni * 16 + lr] = bfbits(o[ni][r]);
    if (lr == 0)
        for (int r = 0; r < 4; ++r) {
            Pm[pbase + quad * 4 + r] = mrow[r];
            Pl[pbase + quad * 4 + r] = lrow[r];
        }
}

// ---------------- combine split-s partials -> ctx[T][H*256] bf16
__global__ __launch_bounds__(256) void attn_combine(const short* __restrict__ Po,
                                                    const float* __restrict__ Pm,
                                                    const float* __restrict__ Pl,
                                                    __hip_bfloat16* __restrict__ ctx) {
    const int h = blockIdx.x;      // 0..7
    const int tt = blockIdx.y;     // 0..127
    const int tid = threadIdx.x;   // 0..255
    __shared__ float wgt[NS_][16];
    const size_t b = ((size_t)h * 128 + tt) * NS_;
    if (tid < 16) {
        const int row = tid;
        float m[NS_], l[NS_];
        float M = -3e38f;
        for (int ns = 0; ns < NS_; ++ns) {
            m[ns] = Pm[(b + ns) * 16 + row];
            l[ns] = Pl[(b + ns) * 16 + row];
            M = fmaxf(M, m[ns]);
        }
        float denom = 0.f, wv[NS_];
        for (int ns = 0; ns < NS_; ++ns) {
            wv[ns] = exp2f(m[ns] - M);
            denom += wv[ns] * l[ns];
        }
        float rd = 1.f / denom;
        for (int ns = 0; ns < NS_; ++ns) wgt[ns][row] = wv[ns] * rd;
    }
    __syncthreads();
    const int d = tid;
    for (int row = 0; row < 16; ++row) {
        float acc = 0.f;
        for (int ns = 0; ns < NS_; ++ns)
            acc += wgt[ns][row] * b2f(Po[((b + ns) * 16 + row) * 256 + d]);
        int t = tt * 16 + row;
        ctx[(size_t)t * (H_ * 256) + h * 256 + d] = __hip_bfloat16(acc);
    }
}

extern "C" void kernel_launch(void* const* d_in, const int* in_sizes, int n_in,
                              void* d_out, int out_size, void* d_ws, size_t ws_size,
                              hipStream_t stream) {
    const float* x       = (const float*)d_in[0];
    const float* Wq      = (const float*)d_in[1];
    const float* Wk      = (const float*)d_in[2];
    const float* Wv      = (const float*)d_in[3];
    const float* Wo      = (const float*)d_in[4];
    const float* q_scale = (const float*)d_in[5];
    const float* k_scale = (const float*)d_in[6];
    const float* k_cache = (const float*)d_in[7];
    const float* v_cache = (const float*)d_in[8];
    const float* cosd    = (const float*)d_in[9];
    const float* sind    = (const float*)d_in[10];
    float* out = (float*)d_out;   // reference output dtype is float32

    char* p = (char*)d_ws;
    float* q_f32 = (float*)p;            p += (size_t)T_ * 2048 * 4;   // 16 MB
    float* k_f32 = (float*)p;            p += (size_t)T_ * 1024 * 4;   //  8 MB
    float* v_f32 = (float*)p;            p += (size_t)T_ * 1024 * 4;   //  8 MB
    __hip_bfloat16* Qr = (__hip_bfloat16*)p;  p += (size_t)H_ * T_ * 256 * 2;
    __hip_bfloat16* Kc = (__hip_bfloat16*)p;  p += (size_t)KV_ * SEFF_ * 256 * 2;
    __hip_bfloat16* Vt = (__hip_bfloat16*)p;  p += (size_t)KV_ * 256 * SEFF_ * 2;
    __hip_bfloat16* ctx = (__hip_bfloat16*)p; p += (size_t)T_ * 2048 * 2;
    float* Pm = (float*)p;               p += (size_t)H_ * 128 * NS_ * 16 * 4;
    float* Pl = (float*)p;               p += (size_t)H_ * 128 * NS_ * 16 * 4;
    // partial O aliases the (dead-by-then) q/k/v fp32 staging: 32 MB exactly
    short* Po = (short*)d_ws;

    // QKV projections (fp32 out for norm precision)
    gemm_bt<float, float, false><<<dim3(16, 16), 256, 0, stream>>>(x, Wq, q_f32, T_, 2048, D_);
    gemm_bt<float, float, false><<<dim3(8, 16), 256, 0, stream>>>(x, Wk, k_f32, T_, 1024, D_);
    gemm_bt<float, float, false><<<dim3(8, 16), 256, 0, stream>>>(x, Wv, v_f32, T_, 1024, D_);

    // norm + rope
    norm_rope<<<T_ * H_, 256, 0, stream>>>(q_f32, q_scale, cosd, sind, Qr, H_, T_, 0);
    norm_rope<<<T_ * KV_, 256, 0, stream>>>(k_f32, k_scale, cosd, sind, Kc, KV_, SEFF_, PREV_);

    // cache merge
    merge_k<<<4096, 256, 0, stream>>>(k_cache, Kc);
    transpose_v<<<dim3(SEFF_ / 64, HD_ / 64, KV_), 256, 0, stream>>>(v_cache, v_f32, Vt);

    // attention (MFMA flash v3: 2-head blocks, dbuf K, global V) + combine
    attn<<<dim3(KV_, T_ / 128, NS_), 1024, 0, stream>>>(Qr, Kc, Vt, Po, Pm, Pl);
    attn_combine<<<dim3(H_, 128), 256, 0, stream>>>(Po, Pm, Pl, ctx);

    // output projection — fp32 output buffer
    gemm_bt<__hip_bfloat16, float, false><<<dim3(20, 16), 256, 0, stream>>>(ctx, Wo, out, T_, D_, 2048);
}

// Round 10
// 905.661 us; speedup vs baseline: 1.4285x; 1.4285x over previous
//
#include <hip/hip_runtime.h>
#include <hip/hip_bf16.h>

#define T_ 2048
#define D_ 2560
#define H_ 8
#define KV_ 4
#define HD_ 256
#define S_ 8192
#define PREV_ 4096
#define SEFF_ 6144
#define NT_ 192          // SEFF/32 key tiles
#define SCALE_ 0.0625f
#define LOG2E_ 1.44269504088896f
#define NS_ 4            // attention key-dim splits

typedef __attribute__((ext_vector_type(8))) short short8;
typedef __attribute__((ext_vector_type(4))) float floatx4;

__device__ inline short8 ld8(const __hip_bfloat16* p) { return *(const short8*)p; }
__device__ inline short8 ld8(const float* p) {
    float4 a = *(const float4*)p;
    float4 b = *(const float4*)(p + 4);
    union { short8 s; __hip_bfloat16 h[8]; } u;
    u.h[0] = __hip_bfloat16(a.x); u.h[1] = __hip_bfloat16(a.y);
    u.h[2] = __hip_bfloat16(a.z); u.h[3] = __hip_bfloat16(a.w);
    u.h[4] = __hip_bfloat16(b.x); u.h[5] = __hip_bfloat16(b.y);
    u.h[6] = __hip_bfloat16(b.z); u.h[7] = __hip_bfloat16(b.w);
    return u.s;
}

__device__ inline short bfbits(float x) {
    __hip_bfloat16 h(x);
    short s;
    __builtin_memcpy(&s, &h, 2);
    return s;
}

__device__ inline float b2f(short u) {
    unsigned int x = ((unsigned int)(unsigned short)u) << 16;
    float f; __builtin_memcpy(&f, &x, 4); return f;
}

// ---------------- fused QKV GEMM: 128x128 tiles over N=4096 (Wq|Wk|Wv)
__global__ __launch_bounds__(256) void gemm_qkv(const float* __restrict__ A,   // x [2048][2560]
                                                const float* __restrict__ Wq,
                                                const float* __restrict__ Wk,
                                                const float* __restrict__ Wv,
                                                float* __restrict__ qo,        // [2048][2048]
                                                float* __restrict__ ko,        // [2048][1024]
                                                float* __restrict__ vo) {      // [2048][1024]
    __shared__ __align__(16) __hip_bfloat16 As[128 * 40];
    __shared__ __align__(16) __hip_bfloat16 Bs[128 * 40];
    const int K = D_;
    const int tid = threadIdx.x;
    const int bm = (int)blockIdx.y * 128, bn = (int)blockIdx.x * 128;
    const int w = tid >> 6, lane = tid & 63, quad = lane >> 4, lr = lane & 15;
    const int wm = (w >> 1) * 64, wn = (w & 1) * 64;
    floatx4 acc[4][4] = {};
    const int row = tid >> 2;
    const int col = (tid & 3) * 8;

    const float* Bp; float* Co; int nb, ldo;
    if (bn < 2048)      { Bp = Wq + (size_t)bn * K;          Co = qo; nb = bn;        ldo = 2048; }
    else if (bn < 3072) { Bp = Wk + (size_t)(bn - 2048) * K; Co = ko; nb = bn - 2048; ldo = 1024; }
    else                { Bp = Wv + (size_t)(bn - 3072) * K; Co = vo; nb = bn - 3072; ldo = 1024; }

    for (int k0 = 0; k0 < K; k0 += 32) {
        __syncthreads();
        for (int p = 0; p < 2; ++p) {
            int r = row + p * 64;
            *(short8*)(&As[r * 40 + col]) = ld8(&A[(size_t)(bm + r) * K + k0 + col]);
            *(short8*)(&Bs[r * 40 + col]) = ld8(&Bp[(size_t)r * K + k0 + col]);
        }
        __syncthreads();
        short8 a[4], b[4];
        for (int mi = 0; mi < 4; ++mi)
            a[mi] = *(const short8*)(&As[(wm + mi * 16 + lr) * 40 + quad * 8]);
        for (int ni = 0; ni < 4; ++ni)
            b[ni] = *(const short8*)(&Bs[(wn + ni * 16 + lr) * 40 + quad * 8]);
        for (int mi = 0; mi < 4; ++mi)
            for (int ni = 0; ni < 4; ++ni)
                acc[mi][ni] = __builtin_amdgcn_mfma_f32_16x16x32_bf16(a[mi], b[ni], acc[mi][ni], 0, 0, 0);
    }
    for (int mi = 0; mi < 4; ++mi)
        for (int ni = 0; ni < 4; ++ni)
            for (int r = 0; r < 4; ++r) {
                int m = bm + wm + mi * 16 + quad * 4 + r;
                int n = nb + wn + ni * 16 + lr;
                Co[(size_t)m * ldo + n] = acc[mi][ni][r];
            }
}

// ---------------- Wo GEMM: 64(M)x128(N) tiles; A=ctx bf16, B=Wo fp32, C=out fp32
__global__ __launch_bounds__(256) void gemm_wo(const __hip_bfloat16* __restrict__ A,  // [2048][2048]
                                               const float* __restrict__ Bm,          // [2560][2048]
                                               float* __restrict__ C) {               // [2048][2560]
    __shared__ __align__(16) __hip_bfloat16 As[64 * 40];
    __shared__ __align__(16) __hip_bfloat16 Bs[128 * 40];
    const int K = 2048, N = D_;
    const int tid = threadIdx.x;
    const int bm = (int)blockIdx.y * 64, bn = (int)blockIdx.x * 128;
    const int w = tid >> 6, lane = tid & 63, quad = lane >> 4, lr = lane & 15;
    const int wn = w * 32;
    floatx4 acc[4][2] = {};
    const int row = tid >> 2;
    const int col = (tid & 3) * 8;

    for (int k0 = 0; k0 < K; k0 += 32) {
        __syncthreads();
        *(short8*)(&As[row * 40 + col]) = ld8(&A[(size_t)(bm + row) * K + k0 + col]);
        for (int p = 0; p < 2; ++p) {
            int r = row + p * 64;
            *(short8*)(&Bs[r * 40 + col]) = ld8(&Bm[(size_t)(bn + r) * K + k0 + col]);
        }
        __syncthreads();
        short8 a[4], b[2];
        for (int mi = 0; mi < 4; ++mi)
            a[mi] = *(const short8*)(&As[(mi * 16 + lr) * 40 + quad * 8]);
        for (int ni = 0; ni < 2; ++ni)
            b[ni] = *(const short8*)(&Bs[(wn + ni * 16 + lr) * 40 + quad * 8]);
        for (int mi = 0; mi < 4; ++mi)
            for (int ni = 0; ni < 2; ++ni)
                acc[mi][ni] = __builtin_amdgcn_mfma_f32_16x16x32_bf16(a[mi], b[ni], acc[mi][ni], 0, 0, 0);
    }
    for (int mi = 0; mi < 4; ++mi)
        for (int ni = 0; ni < 2; ++ni)
            for (int r = 0; r < 4; ++r) {
                int m = bm + mi * 16 + quad * 4 + r;
                int n = bn + wn + ni * 16 + lr;
                C[(size_t)m * N + n] = acc[mi][ni][r];
            }
}

// ---------------- RMSNorm + RoPE (fp32), output bf16 into [head][t(+off)][256] layout
__global__ __launch_bounds__(256) void norm_rope(const float* __restrict__ src,
                                                 const float* __restrict__ scale,
                                                 const float* __restrict__ cosd,
                                                 const float* __restrict__ sind,
                                                 __hip_bfloat16* __restrict__ dst,
                                                 int nh, int smax, int toff) {
    const int rowid = blockIdx.x;
    const int t = rowid / nh, hh = rowid % nh;
    const int d = threadIdx.x;
    __shared__ float ybuf[256];
    __shared__ float wsum[4];
    float x = src[(size_t)t * (nh * 256) + hh * 256 + d];
    float ss = x * x;
    for (int m = 1; m < 64; m <<= 1) ss += __shfl_xor(ss, m);
    if ((d & 63) == 0) wsum[d >> 6] = ss;
    __syncthreads();
    float tot = wsum[0] + wsum[1] + wsum[2] + wsum[3];
    float inv = rsqrtf(tot * (1.0f / 256.0f) + 1e-6f);
    float y = x * inv * (1.0f + scale[d]);
    ybuf[d] = y;
    __syncthreads();
    float rot = (d < 128) ? -ybuf[d + 128] : ybuf[d - 128];
    float cv = cosd[(size_t)t * 256 + d];
    float sv = sind[(size_t)t * 256 + d];
    float out = y * cv + rot * sv;
    dst[((size_t)hh * smax + (t + toff)) * 256 + d] = __hip_bfloat16(out);
}

// ---------------- old K cache (fp32) -> Kc[g][s][256] bf16
__global__ __launch_bounds__(256) void merge_k(const float* __restrict__ kin,
                                               __hip_bfloat16* __restrict__ Kc) {
    int rid = blockIdx.x * 4 + (threadIdx.x >> 6);
    int lane = threadIdx.x & 63;
    int g = rid >> 12, s = rid & 4095;
    float4 v = *(const float4*)&kin[((size_t)s * KV_ + g) * 256 + lane * 4];
    __hip_bfloat16* dst = &Kc[((size_t)g * SEFF_ + s) * 256 + lane * 4];
    union { unsigned long long u; __hip_bfloat16 h[4]; } pk;
    pk.h[0] = __hip_bfloat16(v.x); pk.h[1] = __hip_bfloat16(v.y);
    pk.h[2] = __hip_bfloat16(v.z); pk.h[3] = __hip_bfloat16(v.w);
    *(unsigned long long*)(void*)dst = pk.u;
}

// ---------------- V -> Vt2[g][tile][d][32] bf16  (tile-blocked transpose)
__global__ __launch_bounds__(256) void transpose_v(const float* __restrict__ vin,
                                                   const float* __restrict__ vnew,
                                                   __hip_bfloat16* __restrict__ Vt2) {
    __shared__ __hip_bfloat16 tile[64][65];
    const int g = blockIdx.z;
    const int d0 = blockIdx.y * 64;
    const int s0 = blockIdx.x * 64;
    const int tid = threadIdx.x;
    for (int p = 0; p < 16; ++p) {
        int idx = p * 256 + tid;
        int r = idx >> 6, cc = idx & 63;   // r = s offset, cc = d offset
        int s = s0 + r, d = d0 + cc;
        float v;
        if (s < PREV_) v = vin[((size_t)s * KV_ + g) * 256 + d];
        else           v = vnew[(size_t)(s - PREV_) * 1024 + g * 256 + d];
        tile[r][cc] = __hip_bfloat16(v);
    }
    __syncthreads();
    for (int p = 0; p < 16; ++p) {
        int idx = p * 256 + tid;
        int r = idx >> 6, cc = idx & 63;   // r = d offset, cc = s offset
        int s = s0 + cc, d = d0 + r;
        int tl = s >> 5, j = s & 31;
        Vt2[((size_t)(g * NT_ + tl) * 256 + d) * 32 + j] = tile[cc][r];
    }
}

// ---------------- flash attention v4: 8-wave blocks, packed conflict-free LDS
// K/V staged once per block per 32-key tile; split-s NS_.
__global__ __launch_bounds__(512, 4) void attn(const __hip_bfloat16* __restrict__ Qr,   // [H][T][256]
                                               const __hip_bfloat16* __restrict__ Kc,   // [KV][SEFF][256]
                                               const __hip_bfloat16* __restrict__ Vt2,  // [KV][NT][256][32]
                                               short* __restrict__ Po,                  // [H][128][NS][16][256]
                                               float* __restrict__ Pm,
                                               float* __restrict__ Pl) {
    __shared__ __align__(16) short Ks[8192];      // packed K tile (16 KB)
    __shared__ __align__(16) short Vs[8192];      // packed V tile (16 KB)
    __shared__ __align__(16) short Pls[8][512];   // per-wave P, packed A-layout
    const int h = blockIdx.x;      // 0..7
    const int qb = blockIdx.y;     // 0..15 (128 rows)
    const int ns = blockIdx.z;     // 0..NS_-1
    const int g = h >> 1;
    const int tid = threadIdx.x;   // 0..511
    const int w = tid >> 6, lane = tid & 63, quad = lane >> 4, lr = lane & 15;
    const int qbase = qb * 128;
    const int t0 = qbase + w * 16;

    const short* Qb = (const short*)Qr + ((size_t)h * T_ + t0) * 256;
    const short* Kg = (const short*)Kc + (size_t)g * SEFF_ * 256;
    const short* Vg = (const short*)Vt2 + (size_t)g * NT_ * 8192;

    short8 aq[8];
    for (int kk = 0; kk < 8; ++kk)
        aq[kk] = *(const short8*)(&Qb[(size_t)lr * 256 + kk * 32 + quad * 8]);

    floatx4 o[16] = {};
    float mrow[4] = {-3e38f, -3e38f, -3e38f, -3e38f};
    float lrow[4] = {0.f, 0.f, 0.f, 0.f};
    const float c = SCALE_ * LOG2E_;

    const int nf_w = (PREV_ + t0) >> 5;                   // this wave's masked tile
    const int tiles_b = ((PREV_ + qbase + 112) >> 5) + 1; // block-uniform tile count
    const int per = (tiles_b + NS_ - 1) / NS_;
    const int tstart = ns * per;
    const int tend = min(tstart + per, tiles_b);
    short* pw = &Pls[w][0];

    // staging maps
    const int krow = tid >> 5, kcol = tid & 31;  // K: 16 rows/pass x 32 chunks
    const int vrow = tid >> 2, vcol = tid & 3;   // V: 128 rows/pass x 4 chunks

    for (int tile = tstart; tile < tend; ++tile) {
        const int s0 = tile * 32;
        __syncthreads();
        // stage K (packed): chunk (kr,c): kk=c>>2, quad=c&3, half=kr>>4, lr=kr&15
        for (int p = 0; p < 2; ++p) {
            int kr = p * 16 + krow;
            short8 kv = *(const short8*)&Kg[(size_t)(s0 + kr) * 256 + kcol * 8];
            int kk = kcol >> 2, qd = kcol & 3, hf = kr >> 4, lrr = kr & 15;
            *(short8*)&Ks[((kk * 2 + hf) * 64 + ((qd * 16 + lrr) ^ kk)) * 8] = kv;
        }
        // stage V (packed): row d, chunk c: ni=d>>4, lr=d&15, quad=c
        const short* Vtile = Vg + (size_t)tile * 8192;
        for (int p = 0; p < 2; ++p) {
            int d = p * 128 + vrow;
            short8 vv = *(const short8*)&Vtile[d * 32 + vcol * 8];
            int ni = d >> 4, lrr = d & 15;
            *(short8*)&Vs[(ni * 64 + ((vcol * 16 + lrr) ^ (ni & 7))) * 8] = vv;
        }
        __syncthreads();
        if (tile > nf_w) continue;    // fully masked for this wave (barriers already hit)
        const bool masked = (tile == nf_w);

        floatx4 sc[2];
        for (int half = 0; half < 2; ++half) {
            floatx4 accs = {0.f, 0.f, 0.f, 0.f};
            for (int kk = 0; kk < 8; ++kk) {
                short8 bk = *(const short8*)&Ks[((kk * 2 + half) * 64 + ((quad * 16 + lr) ^ kk)) * 8];
                accs = __builtin_amdgcn_mfma_f32_16x16x32_bf16(aq[kk], bk, accs, 0, 0, 0);
            }
            sc[half] = accs;
        }
        float mnew[4];
        for (int r = 0; r < 4; ++r) {
            float v0 = sc[0][r] * c, v1 = sc[1][r] * c;
            if (masked) {
                int limit = PREV_ + t0 + quad * 4 + r;
                if (s0 + lr > limit)       v0 = -3e38f;
                if (s0 + 16 + lr > limit)  v1 = -3e38f;
            }
            sc[0][r] = v0; sc[1][r] = v1;
            float mx = fmaxf(v0, v1);
            mx = fmaxf(mx, __shfl_xor(mx, 1));
            mx = fmaxf(mx, __shfl_xor(mx, 2));
            mx = fmaxf(mx, __shfl_xor(mx, 4));
            mx = fmaxf(mx, __shfl_xor(mx, 8));
            mnew[r] = fmaxf(mrow[r], mx);
        }
        float alpha[4];
        for (int r = 0; r < 4; ++r) { alpha[r] = exp2f(mrow[r] - mnew[r]); mrow[r] = mnew[r]; }
        for (int r = 0; r < 4; ++r) {
            float p0 = exp2f(sc[0][r] - mnew[r]);
            float p1 = exp2f(sc[1][r] - mnew[r]);
            sc[0][r] = p0; sc[1][r] = p1;
            float s = p0 + p1;
            s += __shfl_xor(s, 1);
            s += __shfl_xor(s, 2);
            s += __shfl_xor(s, 4);
            s += __shfl_xor(s, 8);
            lrow[r] = lrow[r] * alpha[r] + s;
        }
        bool need = (alpha[0] < 1.f) | (alpha[1] < 1.f) | (alpha[2] < 1.f) | (alpha[3] < 1.f);
        if (__any(need)) {
            for (int ni = 0; ni < 16; ++ni)
                for (int r = 0; r < 4; ++r) o[ni][r] *= alpha[r];
        }
        // P: D-layout -> packed A-layout in LDS (chunk = k>>3, row; +k&7)
        for (int half = 0; half < 2; ++half)
            for (int r = 0; r < 4; ++r) {
                int koff = half * 16 + lr;
                pw[((koff >> 3) * 16 + quad * 4 + r) * 8 + (koff & 7)] = bfbits(sc[half][r]);
            }
        __asm__ volatile("s_waitcnt lgkmcnt(0)" ::: "memory");
        short8 ap = *(const short8*)&pw[(quad * 16 + lr) * 8];
        for (int ni = 0; ni < 16; ++ni) {
            short8 bv = *(const short8*)&Vs[(ni * 64 + ((quad * 16 + lr) ^ (ni & 7))) * 8];
            o[ni] = __builtin_amdgcn_mfma_f32_16x16x32_bf16(ap, bv, o[ni], 0, 0, 0);
        }
    }
    // partial epilogue: unnormalized o + (m, l)
    const int tq = qb * 8 + w;
    const size_t pbase = (((size_t)h * 128 + tq) * NS_ + ns) * 16;
    for (int ni = 0; ni < 16; ++ni)
        for (int r = 0; r < 4; ++r)
            Po[(pbase + quad * 4 + r) * 256 + ni * 16 + lr] = bfbits(o[ni][r]);
    if (lr == 0)
        for (int r = 0; r < 4; ++r) {
            Pm[pbase + quad * 4 + r] = mrow[r];
            Pl[pbase + quad * 4 + r] = lrow[r];
        }
}

// ---------------- combine split-s partials -> ctx[T][H*256] bf16
__global__ __launch_bounds__(256) void attn_combine(const short* __restrict__ Po,
                                                    const float* __restrict__ Pm,
                                                    const float* __restrict__ Pl,
                                                    __hip_bfloat16* __restrict__ ctx) {
    const int h = blockIdx.x;
    const int tt = blockIdx.y;
    const int tid = threadIdx.x;
    __shared__ float wgt[NS_][16];
    const size_t b = ((size_t)h * 128 + tt) * NS_;
    if (tid < 16) {
        const int row = tid;
        float m[NS_], l[NS_];
        float M = -3e38f;
        for (int ns = 0; ns < NS_; ++ns) {
            m[ns] = Pm[(b + ns) * 16 + row];
            l[ns] = Pl[(b + ns) * 16 + row];
            M = fmaxf(M, m[ns]);
        }
        float denom = 0.f, wv[NS_];
        for (int ns = 0; ns < NS_; ++ns) {
            wv[ns] = exp2f(m[ns] - M);
            denom += wv[ns] * l[ns];
        }
        float rd = 1.f / denom;
        for (int ns = 0; ns < NS_; ++ns) wgt[ns][row] = wv[ns] * rd;
    }
    __syncthreads();
    const int d = tid;
    for (int row = 0; row < 16; ++row) {
        float acc = 0.f;
        for (int ns = 0; ns < NS_; ++ns)
            acc += wgt[ns][row] * b2f(Po[((b + ns) * 16 + row) * 256 + d]);
        int t = tt * 16 + row;
        ctx[(size_t)t * (H_ * 256) + h * 256 + d] = __hip_bfloat16(acc);
    }
}

extern "C" void kernel_launch(void* const* d_in, const int* in_sizes, int n_in,
                              void* d_out, int out_size, void* d_ws, size_t ws_size,
                              hipStream_t stream) {
    const float* x       = (const float*)d_in[0];
    const float* Wq      = (const float*)d_in[1];
    const float* Wk      = (const float*)d_in[2];
    const float* Wv      = (const float*)d_in[3];
    const float* Wo      = (const float*)d_in[4];
    const float* q_scale = (const float*)d_in[5];
    const float* k_scale = (const float*)d_in[6];
    const float* k_cache = (const float*)d_in[7];
    const float* v_cache = (const float*)d_in[8];
    const float* cosd    = (const float*)d_in[9];
    const float* sind    = (const float*)d_in[10];
    float* out = (float*)d_out;   // reference output dtype is float32

    char* p = (char*)d_ws;
    float* q_f32 = (float*)p;            p += (size_t)T_ * 2048 * 4;   // 16 MB
    float* k_f32 = (float*)p;            p += (size_t)T_ * 1024 * 4;   //  8 MB
    float* v_f32 = (float*)p;            p += (size_t)T_ * 1024 * 4;   //  8 MB
    __hip_bfloat16* Qr  = (__hip_bfloat16*)p;  p += (size_t)H_ * T_ * 256 * 2;
    __hip_bfloat16* Kc  = (__hip_bfloat16*)p;  p += (size_t)KV_ * SEFF_ * 256 * 2;
    __hip_bfloat16* Vt2 = (__hip_bfloat16*)p;  p += (size_t)KV_ * NT_ * 256 * 32 * 2;
    __hip_bfloat16* ctx = (__hip_bfloat16*)p;  p += (size_t)T_ * 2048 * 2;
    float* Pm = (float*)p;               p += (size_t)H_ * 128 * NS_ * 16 * 4;
    float* Pl = (float*)p;               p += (size_t)H_ * 128 * NS_ * 16 * 4;
    // partial O aliases the (dead-by-then) q/k/v fp32 staging: 32 MB exactly
    short* Po = (short*)d_ws;

    // fused QKV projection (fp32 out for norm precision)
    gemm_qkv<<<dim3(32, 16), 256, 0, stream>>>(x, Wq, Wk, Wv, q_f32, k_f32, v_f32);

    // norm + rope
    norm_rope<<<T_ * H_, 256, 0, stream>>>(q_f32, q_scale, cosd, sind, Qr, H_, T_, 0);
    norm_rope<<<T_ * KV_, 256, 0, stream>>>(k_f32, k_scale, cosd, sind, Kc, KV_, SEFF_, PREV_);

    // cache merge
    merge_k<<<4096, 256, 0, stream>>>(k_cache, Kc);
    transpose_v<<<dim3(SEFF_ / 64, HD_ / 64, KV_), 256, 0, stream>>>(v_cache, v_f32, Vt2);

    // attention (MFMA flash v4: packed LDS, tile-blocked V) + combine
    attn<<<dim3(H_, T_ / 128, NS_), 512, 0, stream>>>(Qr, Kc, Vt2, Po, Pm, Pl);
    attn_combine<<<dim3(H_, 128), 256, 0, stream>>>(Po, Pm, Pl, ctx);

    // output projection — fp32 output buffer
    gemm_wo<<<dim3(20, 32), 256, 0, stream>>>(ctx, Wo, out);
}